// Round 1
// baseline (419.193 us; speedup 1.0000x reference)
//
#include <hip/hip_runtime.h>

// LNKillingRelu: out = where(kf<=0, x, x + kf*d)
//   d[b,g,k,n]  = sum_f W[g,f] x[b,f,k,n]          (bf16 MFMA GEMM, K=512)
//   kf[b,g,n]   = sum_{k,l} x[b,g,k,n] G[k,l] d[b,g,l,n]   (fp32, G = sl3 Killing)
// x: [8,512,8,2048] f32, W: [512,512] f32, out same shape as x.
// Block: 256 thr / 4 waves. Tile: 128 g x 128 cols (cols = k*16 + nn -> all 8 k
// planes x 16 n). Wave w owns rows [w*32, w*32+32) -> frags fn=0..7 give all 8 k
// for a (g,nn) lane-locally; epilogue fully in-register, d never hits HBM.

typedef short bf16x8 __attribute__((ext_vector_type(8)));
typedef float f32x4 __attribute__((ext_vector_type(4)));

__device__ __forceinline__ unsigned short f2bf(float f) {
  unsigned int u = __float_as_uint(f);
  u += 0x7fffu + ((u >> 16) & 1u);   // round-to-nearest-even
  return (unsigned short)(u >> 16);
}

__global__ __launch_bounds__(256) void lnkill_fused(
    const float* __restrict__ x, const float* __restrict__ W,
    float* __restrict__ out) {
  // chunked LDS layout: [buf][kg(4)][row(128)][8 bf16] -> dense 16B chunks
  __shared__ __align__(16) short ldsA[2][4096];  // W tile  [kg][m]
  __shared__ __align__(16) short ldsB[2][4096];  // x tile  [kg][c]

  const int tid  = threadIdx.x;
  const int lane = tid & 63;
  const int w    = tid >> 6;     // wave 0..3
  const int cm   = tid & 127;    // staging: column c (B) == row m (A)
  const int h    = tid >> 7;     // staging: f-half (16 f each)

  const int b  = blockIdx.z;
  const int g0 = blockIdx.x * 128;
  const int n0 = blockIdx.y * 16;

  // x[b, f, k, n] flat = ((b*512+f)*8 + k)*2048 + n ; staging col cm -> k=cm>>4, nn=cm&15
  const float* xs   = x + (((size_t)(b * 512 + h * 16)) * 8 + (cm >> 4)) * 2048
                        + n0 + (cm & 15);
  const float* Wrow = W + (size_t)(g0 + cm) * 512 + h * 16;

  f32x4 acc[2][8] = {};  // [fm][fn] ; fn == k plane

  // ---- prologue: stage kt=0 into buf 0 ----
  {
    float xv[16];
#pragma unroll
    for (int j = 0; j < 16; ++j) xv[j] = xs[(size_t)j * 16384];
    float4 wv[4];
    const float4* wp = (const float4*)Wrow;
#pragma unroll
    for (int q = 0; q < 4; ++q) wv[q] = wp[q];
    const float* wf = (const float*)wv;
#pragma unroll
    for (int q = 0; q < 2; ++q) {
      bf16x8 vb, va;
#pragma unroll
      for (int j = 0; j < 8; ++j) {
        vb[j] = (short)f2bf(xv[q * 8 + j]);
        va[j] = (short)f2bf(wf[q * 8 + j]);
      }
      const int kg = h * 2 + q;
      *(bf16x8*)&ldsB[0][(kg * 128 + cm) * 8] = vb;
      *(bf16x8*)&ldsA[0][(kg * 128 + cm) * 8] = va;
    }
  }
  __syncthreads();

  const int klane = lane >> 4;
  const int li    = lane & 15;

  for (int kt = 0; kt < 16; ++kt) {
    const int cur = kt & 1;

    // issue next tile's global loads early (latency hidden under MFMAs)
    float xv[16];
    float4 wv[4];
    if (kt < 15) {
      const float* xp = xs + (size_t)(kt + 1) * 32 * 16384;
#pragma unroll
      for (int j = 0; j < 16; ++j) xv[j] = xp[(size_t)j * 16384];
      const float4* wp = (const float4*)(Wrow + (kt + 1) * 32);
#pragma unroll
      for (int q = 0; q < 4; ++q) wv[q] = wp[q];
    }

    // fragment reads (dense 16B chunks, conflict-free)
    bf16x8 afr[2], bfr[8];
    const short* Ac = ldsA[cur];
    const short* Bc = ldsB[cur];
#pragma unroll
    for (int fm = 0; fm < 2; ++fm)
      afr[fm] = *(const bf16x8*)&Ac[(klane * 128 + w * 32 + fm * 16 + li) * 8];
#pragma unroll
    for (int fn = 0; fn < 8; ++fn)
      bfr[fn] = *(const bf16x8*)&Bc[(klane * 128 + fn * 16 + li) * 8];

#pragma unroll
    for (int fm = 0; fm < 2; ++fm)
#pragma unroll
      for (int fn = 0; fn < 8; ++fn)
        acc[fm][fn] = __builtin_amdgcn_mfma_f32_16x16x32_bf16(
            afr[fm], bfr[fn], acc[fm][fn], 0, 0, 0);

    if (kt < 15) {
      const int nxt = cur ^ 1;
      const float* wf = (const float*)wv;
#pragma unroll
      for (int q = 0; q < 2; ++q) {
        bf16x8 vb, va;
#pragma unroll
        for (int j = 0; j < 8; ++j) {
          vb[j] = (short)f2bf(xv[q * 8 + j]);
          va[j] = (short)f2bf(wf[q * 8 + j]);
        }
        const int kg = h * 2 + q;
        *(bf16x8*)&ldsB[nxt][(kg * 128 + cm) * 8] = vb;
        *(bf16x8*)&ldsA[nxt][(kg * 128 + cm) * 8] = va;
      }
      __syncthreads();
    }
  }

  // ---- epilogue: kf (fp32 x, Killing Gram) + branch + store, all in-register ----
#pragma unroll
  for (int fm = 0; fm < 2; ++fm) {
#pragma unroll
    for (int r = 0; r < 4; ++r) {
      const int g = g0 + w * 32 + fm * 16 + klane * 4 + r;
      const size_t base = ((size_t)(b * 512 + g)) * 16384 + n0 + li;
      float xk[8];
#pragma unroll
      for (int k = 0; k < 8; ++k) xk[k] = x[base + (size_t)k * 2048];
      // c_l = (G x)_l ; G: 12@(0,0),(4,4); -6@(0,4); 6@{1,3},{2,6},{5,7}
      const float c0 = 12.f * xk[0] - 6.f * xk[4];
      const float c4 = 12.f * xk[4] - 6.f * xk[0];
      const float c1 = 6.f * xk[3];
      const float c2 = 6.f * xk[6];
      const float c3 = 6.f * xk[1];
      const float c5 = 6.f * xk[7];
      const float c6 = 6.f * xk[2];
      const float c7 = 6.f * xk[5];
      const float kf = c0 * acc[fm][0][r] + c1 * acc[fm][1][r]
                     + c2 * acc[fm][2][r] + c3 * acc[fm][3][r]
                     + c4 * acc[fm][4][r] + c5 * acc[fm][5][r]
                     + c6 * acc[fm][6][r] + c7 * acc[fm][7][r];
#pragma unroll
      for (int k = 0; k < 8; ++k) {
        const float o = (kf <= 0.f) ? xk[k] : fmaf(kf, acc[fm][k][r], xk[k]);
        out[base + (size_t)k * 2048] = o;
      }
    }
  }
}

extern "C" void kernel_launch(void* const* d_in, const int* in_sizes, int n_in,
                              void* d_out, int out_size, void* d_ws, size_t ws_size,
                              hipStream_t stream) {
  const float* x = (const float*)d_in[0];
  const float* W = (const float*)d_in[1];
  float* out = (float*)d_out;
  // grid: x = g-tile (512/128), y = n-tile (2048/16), z = batch
  dim3 grid(4, 128, 8);
  lnkill_fused<<<grid, dim3(256), 0, stream>>>(x, W, out);
}

// Round 2
// 335.317 us; speedup vs baseline: 1.2501x; 1.2501x over previous
//
#include <hip/hip_runtime.h>

// LNKillingRelu: out = where(kf<=0, x, x + kf*d)
//   d[b,g,k,n]  = sum_f W[g,f] x[b,f,k,n]          (bf16 MFMA GEMM, K=512)
//   kf[b,g,n]   = sum_{k,l} x[b,g,k,n] G[k,l] d[b,g,l,n]   (fp32, G = sl3 Killing)
// x: [8,512,8,2048] f32, W: [512,512] f32, out same shape as x.
//
// R2: 512 thr / 8 waves (wave = 16 g-rows x 128 cols; acc 32 regs not 64 ->
// unified VGPR+AGPR ~115 < 128 -> 4 waves/SIMD, 2x occupancy vs R1) +
// XCD-chunked block swizzle (each XCD owns one batch b; 4 g-tile blocks
// sharing an x-slice are consecutive on one XCD -> slice read from HBM once).
// cols = k*16 + nn -> one wave's 8 B-frags give all 8 k lane-locally;
// epilogue (Killing form + branch) fully in-register, d never hits HBM.

typedef short bf16x8 __attribute__((ext_vector_type(8)));
typedef float f32x4 __attribute__((ext_vector_type(4)));

__device__ __forceinline__ unsigned short f2bf(float f) {
  unsigned int u = __float_as_uint(f);
  u += 0x7fffu + ((u >> 16) & 1u);   // round-to-nearest-even
  return (unsigned short)(u >> 16);
}

__global__ __launch_bounds__(512, 4) void lnkill_fused(
    const float* __restrict__ x, const float* __restrict__ W,
    float* __restrict__ out) {
  // chunked LDS: [buf][kg(4)][row(128)][8 bf16] -> dense 16B chunks, 0 conflicts
  __shared__ __align__(16) short ldsA[2][4096];  // W tile [kg][m]
  __shared__ __align__(16) short ldsB[2][4096];  // x tile [kg][c]

  const int tid  = threadIdx.x;
  const int lane = tid & 63;
  const int w    = tid >> 6;      // wave 0..7

  // XCD-chunked swizzle: logical l = gt + 4*(nt + 128*b); bid%8 -> XCD
  const int bid = blockIdx.x;                 // 0..4095
  const int l   = (bid & 7) * 512 + (bid >> 3);
  const int gt  = l & 3;
  const int nt  = (l >> 2) & 127;
  const int b   = l >> 9;
  const int g0  = gt * 128;
  const int n0  = nt * 16;

  // staging: thread -> (col/row cm = tid&127, f-subgroup fg = tid>>7 of 8 f's)
  const int cm = tid & 127;
  const int fg = tid >> 7;        // 0..3
  // x col cm -> k = cm>>4, nn = cm&15 ; f = kt*32 + fg*8 + j
  const float* xs   = x + (((size_t)(b * 512 + fg * 8)) * 8 + (cm >> 4)) * 2048
                        + n0 + (cm & 15);
  const float* Wrow = W + (size_t)(g0 + cm) * 512 + fg * 8;

  f32x4 acc[8] = {};   // [fn] ; fn == k plane

  // ---- prologue: stage kt=0 into buf 0 ----
  {
    float xv[8];
#pragma unroll
    for (int j = 0; j < 8; ++j) xv[j] = xs[(size_t)j * 16384];
    float4 wv[2];
    const float4* wp = (const float4*)Wrow;
    wv[0] = wp[0]; wv[1] = wp[1];
    const float* wf = (const float*)wv;
    bf16x8 vb, va;
#pragma unroll
    for (int j = 0; j < 8; ++j) {
      vb[j] = (short)f2bf(xv[j]);
      va[j] = (short)f2bf(wf[j]);
    }
    *(bf16x8*)&ldsB[0][(fg * 128 + cm) * 8] = vb;
    *(bf16x8*)&ldsA[0][(fg * 128 + cm) * 8] = va;
  }
  __syncthreads();

  const int klane = lane >> 4;
  const int li    = lane & 15;

  for (int kt = 0; kt < 16; ++kt) {
    const int cur = kt & 1;

    // issue next tile's global loads early (hidden under ds_read+MFMA)
    float xv[8];
    float4 wv[2];
    if (kt < 15) {
      const float* xp = xs + (size_t)(kt + 1) * 32 * 16384;
#pragma unroll
      for (int j = 0; j < 8; ++j) xv[j] = xp[(size_t)j * 16384];
      const float4* wp = (const float4*)(Wrow + (kt + 1) * 32);
      wv[0] = wp[0]; wv[1] = wp[1];
    }

    // fragment reads (dense 16B chunks)
    bf16x8 afr, bfr[8];
    const short* Ac = ldsA[cur];
    const short* Bc = ldsB[cur];
    afr = *(const bf16x8*)&Ac[(klane * 128 + w * 16 + li) * 8];
#pragma unroll
    for (int fn = 0; fn < 8; ++fn)
      bfr[fn] = *(const bf16x8*)&Bc[(klane * 128 + fn * 16 + li) * 8];

#pragma unroll
    for (int fn = 0; fn < 8; ++fn)
      acc[fn] = __builtin_amdgcn_mfma_f32_16x16x32_bf16(afr, bfr[fn], acc[fn], 0, 0, 0);

    if (kt < 15) {
      const int nxt = cur ^ 1;
      const float* wf = (const float*)wv;
      bf16x8 vb, va;
#pragma unroll
      for (int j = 0; j < 8; ++j) {
        vb[j] = (short)f2bf(xv[j]);
        va[j] = (short)f2bf(wf[j]);
      }
      *(bf16x8*)&ldsB[nxt][(fg * 128 + cm) * 8] = vb;
      *(bf16x8*)&ldsA[nxt][(fg * 128 + cm) * 8] = va;
      __syncthreads();
    }
  }

  // ---- epilogue: kf (fp32 x, Killing Gram) + branch + store, in-register ----
  // D frag: col = li (nn), row = klane*4 + r  (within the wave's 16 g-rows)
#pragma unroll
  for (int r = 0; r < 4; ++r) {
    const int g = g0 + w * 16 + klane * 4 + r;
    const size_t base = ((size_t)(b * 512 + g)) * 16384 + n0 + li;
    float xk[8];
#pragma unroll
    for (int k = 0; k < 8; ++k) xk[k] = x[base + (size_t)k * 2048];
    // c_l = (G x)_l ; G: 12@(0,0),(4,4); -6@(0,4); 6@{1,3},{2,6},{5,7}
    const float c0 = 12.f * xk[0] - 6.f * xk[4];
    const float c4 = 12.f * xk[4] - 6.f * xk[0];
    const float c1 = 6.f * xk[3];
    const float c2 = 6.f * xk[6];
    const float c3 = 6.f * xk[1];
    const float c5 = 6.f * xk[7];
    const float c6 = 6.f * xk[2];
    const float c7 = 6.f * xk[5];
    const float kf = c0 * acc[0][r] + c1 * acc[1][r]
                   + c2 * acc[2][r] + c3 * acc[3][r]
                   + c4 * acc[4][r] + c5 * acc[5][r]
                   + c6 * acc[6][r] + c7 * acc[7][r];
#pragma unroll
    for (int k = 0; k < 8; ++k) {
      const float o = (kf <= 0.f) ? xk[k] : fmaf(kf, acc[k][r], xk[k]);
      out[base + (size_t)k * 2048] = o;
    }
  }
}

extern "C" void kernel_launch(void* const* d_in, const int* in_sizes, int n_in,
                              void* d_out, int out_size, void* d_ws, size_t ws_size,
                              hipStream_t stream) {
  const float* x = (const float*)d_in[0];
  const float* W = (const float*)d_in[1];
  float* out = (float*)d_out;
  // 1D grid, swizzled in-kernel: 4 g-tiles x 128 n-tiles x 8 batches = 4096
  lnkill_fused<<<dim3(4096), dim3(512), 0, stream>>>(x, W, out);
}